// Round 1
// baseline (98.576 us; speedup 1.0000x reference)
//
#include <hip/hip_runtime.h>

// Chamfer loss: B=8, P=32, N=M=1024, fp32 in, scalar fp32 out.
// Reference quirk: x[bp,m,c] = rp[bp, (3m+c)%M, (3m+c)>>10]  (torch permute+reshape).
//
// R5: move the distance computation to the matrix pipe. dist = xx + yy - 2x.y is
// a K=3 matmul; emulate fp32 via 3-way bf16 splits (h0+h1+h2, residuals 2^-9 each).
// 30 K-slots per (row,col): 8 cross-terms per coord x3 = 24, plus xx as (p_i,1)
// and yy as (1,q_i). One 32x32 tile = 2x mfma_f32_32x32x16_bf16 with acc chaining,
// C seeded 0. Error ~2^-27 * |terms| ~ 1e-7 (same order as reference's own fp32
// rounding). VALU keeps only the mins: 16 v_min (row) + ~9 min3 (col) per tile
// => ~1.75 VALU/dist vs 6 in R4b; MFMA-bound at ~16.5K cyc/CU.
//
// Layout: 256 blocks (1 bp) x 512 threads (8 waves). LDS: B panel 1024x80B
// (80B stride => conflict-free b128 frag reads), A panel 1024x64B; after A-frag
// loads the A panel is dead and its first 32KB is reused as colW[8][1024].
// Wave owns 128 rows = 4 stripes of 32; loops 32 N-tiles with B prefetch.
// Row-min: per-lane regs rmin[4][16] reduced by DPP ror(1,2,4,8)+swizzle xor16
// (rows = f(reg,lane>>5) only, cols = lane&31 — reduction needs no row identity).
// Col-min: per-tile min3-tree over 16 regs x 4 stripes, bpermute xor32 merge,
// one colW write per tile; cross-wave merge + sums in the epilogue.

#define MM 1024
#define NN 1024
#define THREADS 512
#define NWAVES 8
#define FINF 3.4e38f

typedef float f32x16 __attribute__((ext_vector_type(16)));
typedef __bf16 bf16x8 __attribute__((ext_vector_type(8)));

#define B_STRIDE 80                       // bytes per y-column (40 ushort slots)
#define A_STRIDE 64                       // bytes per x-row (32 ushort slots)
#define B_OFF 0
#define A_OFF (NN * B_STRIDE)             // 81920
#define CW_OFF A_OFF                      // overlay: colW[8][1024] f32 = 32KB
#define RS_OFF (A_OFF + MM * A_STRIDE)    // 147456
#define RED_OFF (RS_OFF + 64)
#define LDS_BYTES (RED_OFF + 64)          // 147584

__device__ __forceinline__ unsigned short bf16_rne(float v) {
    unsigned u = __float_as_uint(v);
    u = u + 0x7FFFu + ((u >> 16) & 1u);
    return (unsigned short)(u >> 16);
}
__device__ __forceinline__ float bf16f(unsigned short h) {
    return __uint_as_float(((unsigned)h) << 16);
}
struct S3 { unsigned short h0, h1, h2; };
__device__ __forceinline__ S3 split3(float v) {
    S3 o;
    o.h0 = bf16_rne(v);
    float r = v - bf16f(o.h0);
    o.h1 = bf16_rne(r);
    float r2 = r - bf16f(o.h1);
    o.h2 = bf16_rne(r2);
    return o;
}
__device__ __forceinline__ unsigned pk(unsigned short a, unsigned short b) {
    return (unsigned)a | ((unsigned)b << 16);
}
__device__ __forceinline__ float min3f(float a, float b, float c) {
    return fminf(fminf(a, b), c);   // folds to v_min3_f32
}
template <int CTRL>
__device__ __forceinline__ float dpp_ror_min(float v) {
    int vi = __float_as_int(v);
    int t  = __builtin_amdgcn_update_dpp(vi, vi, CTRL, 0xf, 0xf, true);
    return fminf(v, __int_as_float(t));
}

__global__ __launch_bounds__(THREADS, 2)
void chamfer_kernel(const float* __restrict__ nrf,   // (BP, N, 3) -> y
                    const float* __restrict__ rp,    // (BP, M, 3) -> x (scrambled)
                    float* __restrict__ out,
                    float inv_bpm, float inv_bpn) {
    __shared__ __align__(16) unsigned char smem[LDS_BYTES];
    unsigned char* Bb = smem + B_OFF;
    unsigned short* As = (unsigned short*)(smem + A_OFF);
    float* colW = (float*)(smem + CW_OFF);
    float* rowsumS = (float*)(smem + RS_OFF);
    float* redS = (float*)(smem + RED_OFF);

    const int bp = blockIdx.x;
    const int tid = threadIdx.x;
    const int lane = tid & 63;
    const int wave = tid >> 6;
    const int l31 = lane & 31;
    const int lh = lane >> 5;
    const unsigned short ONE = 0x3F80;

    const float* yB = nrf + (size_t)bp * NN * 3;
    const float* xB = rp + (size_t)bp * MM * 3;

    // ---- B panel: per col slots (b = y split, q = yy split)
    // per coord c (6 slots): b.h0, b.h1, b.h0, b.h1, b.h2, b.h0
    // 18-20: ONE (pairs A's xx), 21-23: q0..q2, 24-29: b.h2,b.h1 per coord, 30-39: 0
    for (int c = tid; c < NN; c += THREADS) {
        float y0 = yB[c * 3 + 0], y1 = yB[c * 3 + 1], y2 = yB[c * 3 + 2];
        float yy = __builtin_fmaf(y0, y0, __builtin_fmaf(y1, y1, y2 * y2));
        S3 b0 = split3(y0), b1 = split3(y1), b2 = split3(y2), q = split3(yy);
        uint4* dst = (uint4*)(Bb + c * B_STRIDE);
        dst[0] = make_uint4(pk(b0.h0, b0.h1), pk(b0.h0, b0.h1), pk(b0.h2, b0.h0), pk(b1.h0, b1.h1));
        dst[1] = make_uint4(pk(b1.h0, b1.h1), pk(b1.h2, b1.h0), pk(b2.h0, b2.h1), pk(b2.h0, b2.h1));
        dst[2] = make_uint4(pk(b2.h2, b2.h0), pk(ONE, ONE), pk(ONE, q.h0), pk(q.h1, q.h2));
        dst[3] = make_uint4(pk(b0.h2, b0.h1), pk(b1.h2, b1.h1), pk(b2.h2, b2.h1), 0u);
        dst[4] = make_uint4(0u, 0u, 0u, 0u);
    }
    // ---- A panel: per row slots (a = -2x split, p = xx split)
    // per coord c: a.h0, a.h0, a.h1, a.h1, a.h0, a.h2
    // 18-20: p0..p2, 21-23: ONE (pairs B's yy), 24-29: a.h1,a.h2 per coord, 30-31: 0
    for (int m = tid; m < MM; m += THREADS) {
        int k = 3 * m;
        float x0 = xB[((k    ) & (MM - 1)) * 3 + ((k    ) >> 10)];
        float x1 = xB[((k + 1) & (MM - 1)) * 3 + ((k + 1) >> 10)];
        float x2 = xB[((k + 2) & (MM - 1)) * 3 + ((k + 2) >> 10)];
        float xx = __builtin_fmaf(x0, x0, __builtin_fmaf(x1, x1, x2 * x2));
        S3 a0 = split3(-2.0f * x0), a1 = split3(-2.0f * x1), a2 = split3(-2.0f * x2);
        S3 p = split3(xx);
        uint4* dst = (uint4*)((unsigned char*)As + m * A_STRIDE);
        dst[0] = make_uint4(pk(a0.h0, a0.h0), pk(a0.h1, a0.h1), pk(a0.h0, a0.h2), pk(a1.h0, a1.h0));
        dst[1] = make_uint4(pk(a1.h1, a1.h1), pk(a1.h0, a1.h2), pk(a2.h0, a2.h0), pk(a2.h1, a2.h1));
        dst[2] = make_uint4(pk(a2.h0, a2.h2), pk(p.h0, p.h1), pk(p.h2, ONE), pk(ONE, ONE));
        dst[3] = make_uint4(pk(a0.h1, a0.h2), pk(a1.h1, a1.h2), pk(a2.h1, a2.h2), 0u);
    }
    __syncthreads();

    // ---- A-fragment loads (once; rows fixed per wave): 4 stripes x 2 K-halves
    const int m0 = wave * 128;
    bf16x8 af[4][2];
    #pragma unroll
    for (int s = 0; s < 4; ++s) {
        #pragma unroll
        for (int h = 0; h < 2; ++h)
            af[s][h] = *(const bf16x8*)(As + (m0 + s * 32 + l31) * 32 + h * 16 + lh * 8);
    }
    __syncthreads();   // after this, A panel's first 32KB is colW

    float rmin[4][16];
    #pragma unroll
    for (int s = 0; s < 4; ++s)
        #pragma unroll
        for (int j = 0; j < 16; ++j) rmin[s][j] = FINF;

    f32x16 Z = {};
    const unsigned char* bptr = Bb + l31 * B_STRIDE + lh * 16;
    const int xaddr32 = (lane ^ 32) << 2;
    float* colWrow = colW + wave * 1024;

    bf16x8 bf0 = *(const bf16x8*)(bptr);
    bf16x8 bf1 = *(const bf16x8*)(bptr + 32);
    for (int t = 0; t < 32; ++t) {
        // prefetch next tile's B-frags (last iter reads dead LDS, values unused)
        const unsigned char* np = bptr + 32 * B_STRIDE;
        bf16x8 nb0 = *(const bf16x8*)(np);
        bf16x8 nb1 = *(const bf16x8*)(np + 32);

        float cm = FINF;
        #pragma unroll
        for (int s = 0; s < 4; ++s) {
            f32x16 acc = __builtin_amdgcn_mfma_f32_32x32x16_bf16(af[s][0], bf0, Z, 0, 0, 0);
            acc = __builtin_amdgcn_mfma_f32_32x32x16_bf16(af[s][1], bf1, acc, 0, 0, 0);
            #pragma unroll
            for (int j = 0; j < 16; ++j) rmin[s][j] = fminf(rmin[s][j], acc[j]);
            float u0 = min3f(acc[0], acc[1], acc[2]);
            float u1 = min3f(acc[3], acc[4], acc[5]);
            float u2 = min3f(acc[6], acc[7], acc[8]);
            float u3 = min3f(acc[9], acc[10], acc[11]);
            float u4 = min3f(acc[12], acc[13], acc[14]);
            cm = fminf(cm, fminf(min3f(u0, u1, u2), min3f(u3, u4, acc[15])));
        }
        // merge the two lane-halves (rows 4*lh interleave) -> full 128-row col-min
        int pz = __builtin_amdgcn_ds_bpermute(xaddr32, __float_as_int(cm));
        cm = fminf(cm, __int_as_float(pz));
        if (lh == 0) colWrow[t * 32 + l31] = cm;

        bf0 = nb0; bf1 = nb1; bptr = np;
    }

    // ---- row-min reduce: min over lanes 0..31 (cols) per half; rows = f(j,lh)
    float rowsum = 0.0f;
    #pragma unroll
    for (int s = 0; s < 4; ++s) {
        #pragma unroll
        for (int j = 0; j < 16; ++j) {
            float v = rmin[s][j];
            v = dpp_ror_min<0x121>(v);   // row_ror:1
            v = dpp_ror_min<0x122>(v);   // row_ror:2
            v = dpp_ror_min<0x124>(v);   // row_ror:4
            v = dpp_ror_min<0x128>(v);   // row_ror:8 -> per-16 min
            int sw = __builtin_amdgcn_ds_swizzle(__float_as_int(v), 0x401F); // xor16
            v = fminf(v, __int_as_float(sw));
            rowsum += v;                 // each (s,j,lh) is a distinct row, all covered
        }
    }
    if (l31 == 0) rowsumS[wave * 2 + lh] = rowsum;
    __syncthreads();

    // ---- cross-wave col-min merge + column sum
    float csum = 0.0f;
    for (int c = tid; c < NN; c += THREADS) {
        float v = colW[c];
        #pragma unroll
        for (int w = 1; w < NWAVES; ++w) v = fminf(v, colW[w * 1024 + c]);
        csum += v;
    }
    #pragma unroll
    for (int off = 32; off > 0; off >>= 1) csum += __shfl_xor(csum, off, 64);
    if (lane == 0) redS[wave] = csum;
    __syncthreads();

    if (tid == 0) {
        float rs = 0.0f, cs = 0.0f;
        #pragma unroll
        for (int w = 0; w < NWAVES; ++w) cs += redS[w];
        #pragma unroll
        for (int w = 0; w < 2 * NWAVES; ++w) rs += rowsumS[w];
        atomicAdd(out, rs * inv_bpm + cs * inv_bpn);
    }
}

extern "C" void kernel_launch(void* const* d_in, const int* in_sizes, int n_in,
                              void* d_out, int out_size, void* d_ws, size_t ws_size,
                              hipStream_t stream) {
    const float* nrf = (const float*)d_in[0];  // (B,P,N,3)
    const float* rp  = (const float*)d_in[1];  // (B,P,M,3)
    float* out = (float*)d_out;

    const int BP = in_sizes[1] / (MM * 3);     // 256
    const float inv_bpm = 1.0f / (float)(BP * MM);
    const float inv_bpn = 1.0f / (float)(BP * NN);

    (void)hipMemsetAsync(out, 0, sizeof(float), stream);
    chamfer_kernel<<<BP, THREADS, 0, stream>>>(nrf, rp, out, inv_bpm, inv_bpn);
}